// Round 6
// baseline (323.230 us; speedup 1.0000x reference)
//
#include <hip/hip_runtime.h>
#include <type_traits>

typedef __bf16 bf16;
typedef __attribute__((ext_vector_type(8))) __bf16 bf16x8;
typedef __attribute__((ext_vector_type(4))) float f32x4;
typedef __attribute__((ext_vector_type(16))) float f32x16;

constexpr int Bc = 4, Tc = 2048, Cc = 1024, Hc = 16;
constexpr int Mrows = Bc * Tc;   // 8192
constexpr int N3 = 3 * Cc;       // 3072

#define GLOAD(gp, lp)                                                          \
  __builtin_amdgcn_global_load_lds(                                           \
      (const __attribute__((address_space(1))) void*)(gp),                     \
      (__attribute__((address_space(3))) void*)(lp), 16, 0, 0)

__device__ __forceinline__ uint32_t pk2(float a, float b) {
  uint16_t x = __builtin_bit_cast(uint16_t, (bf16)a);
  uint16_t y = __builtin_bit_cast(uint16_t, (bf16)b);
  return (uint32_t)x | ((uint32_t)y << 16);
}

template <int N>
__device__ __forceinline__ void vm_wait() {
  static_assert(N == 3 || N == 4, "");
  if constexpr (N == 3)
    asm volatile("s_waitcnt vmcnt(3)" ::: "memory");
  else
    asm volatile("s_waitcnt vmcnt(4)" ::: "memory");
}

__device__ __forceinline__ void barx() {
  asm volatile("" ::: "memory");
  __builtin_amdgcn_s_barrier();
  asm volatile("" ::: "memory");
}

// ---------------- cast fp32 -> bf16, 8 elems/thread ----------------
__global__ __launch_bounds__(256) void cast_bf16_kernel(
    const float* __restrict__ in, bf16* __restrict__ out, int n8) {
  int i = blockIdx.x * blockDim.x + threadIdx.x;
  int stride = gridDim.x * blockDim.x;
  for (; i < n8; i += stride) {
    const float4* p = (const float4*)(in + (long)i * 8);
    float4 a = p[0], b = p[1];
    bf16x8 v;
    v[0] = (bf16)a.x; v[1] = (bf16)a.y; v[2] = (bf16)a.z; v[3] = (bf16)a.w;
    v[4] = (bf16)b.x; v[5] = (bf16)b.y; v[6] = (bf16)b.z; v[7] = (bf16)b.w;
    *(bf16x8*)(out + (long)i * 8) = v;
  }
}

// ---- transpose + cast: in[rows][cols] f32 -> out[cols][rows] bf16.
// Output rows < srows get multiplied by scale (fold 1/sqrt(D) into Wq).
__global__ __launch_bounds__(256) void transpose_cast_kernel(
    const float* __restrict__ in, bf16* __restrict__ out, int rows, int cols,
    float scale, int srows) {
  __shared__ float tile[32][33];
  int tx = threadIdx.x, ty = threadIdx.y;
  int r0 = blockIdx.y * 32, c0 = blockIdx.x * 32;
#pragma unroll
  for (int i = 0; i < 4; i++)
    tile[ty + 8 * i][tx] = in[(long)(r0 + ty + 8 * i) * cols + c0 + tx];
  __syncthreads();
#pragma unroll
  for (int i = 0; i < 4; i++) {
    int orow = c0 + ty + 8 * i;
    float v = tile[tx][ty + 8 * i];
    if (orow < srows) v *= scale;
    out[(long)orow * rows + r0 + tx] = (bf16)v;
  }
}

// ---- transpose V part of QKV: Y[.,2048+h*64+d] -> Vt[bh][d][t'] with
// quad-swapped t (bits 2<->3 of t&15) so PV reads b128 without lane exchange.
__global__ __launch_bounds__(256) void transpose_v_kernel(
    const bf16* __restrict__ Y, bf16* __restrict__ Vt) {
  __shared__ bf16 tile[32][33];
  int tx = threadIdx.x, ty = threadIdx.y;
  int t0 = blockIdx.x * 32;
  int d0 = blockIdx.y * 32;
  int bh = blockIdx.z;
  int b = bh >> 4, h = bh & 15;
  const bf16* src = Y + (long)(b * Tc) * N3 + 2 * Cc + h * 64;
#pragma unroll
  for (int i = 0; i < 4; i++)
    tile[ty + 8 * i][tx] = src[(long)(t0 + ty + 8 * i) * N3 + d0 + tx];
  __syncthreads();
  bf16* dst = Vt + (long)bh * 64 * Tc;
  int txp = (tx & 0x13) | ((tx & 4) << 1) | ((tx & 8) >> 1);  // quad swap
#pragma unroll
  for (int i = 0; i < 4; i++)
    dst[(long)(d0 + ty + 8 * i) * Tc + t0 + txp] = tile[tx][ty + 8 * i];
}

// ---------------- 8-phase GEMM: C[M,N] = A[M,K] * Bt[N,K]^T + bias ----------
// BM x 256 tile, BK=64 (two 32-wide K-halves), 512 thr = 8 waves (2M x 4N).
// LDS half-tiles are [rows][32] bf16 (64 B rows): bank = 16*(row&1)+4*chunk,
// so wave64 ds_read_b128 hits the even-8 structural floor with LINEAR
// global_load_lds staging (no swizzle needed).
// Pipeline: stage order per tile t+1 = [A-Klo, B-Klo, A-Khi, B-Khi], one
// half-tile per phase; fragment read-ahead one phase early; counted
// vmcnt(ALD+2) at phases 1 and 3 only (never 0 in-loop).
template <int BM, typename OutT>
__global__ __launch_bounds__(512, 2) void gemm8_kernel(
    const bf16* __restrict__ A, const bf16* __restrict__ Bt,
    const float* __restrict__ bias, OutT* __restrict__ C, int M, int N, int K,
    int sb, int NMB) {
  constexpr int MREP = BM / 32;   // M-frags per wave (8 or 4)
  constexpr int ALD = BM / 128;   // gloads/thread per A-half (2 or 1)
  constexpr int VMW = ALD + 2;    // steady-state counted vmcnt
  __shared__ __align__(16) bf16 Abuf[2][2][BM * 32];
  __shared__ __align__(16) bf16 Bbuf[2][2][256 * 32];
  const int tid = threadIdx.x;
  const int w = tid >> 6, l = tid & 63;
  const int wm = w >> 2, wn = w & 3;
  const int lr = l & 15, lc = l >> 4;
  // XCD-aware bijective swizzle (nwg % 8 == 0 guaranteed by launch)
  const int nwg = gridDim.x;
  const int bid = blockIdx.x;
  const int swz = (bid & 7) * (nwg >> 3) + (bid >> 3);
  const int bm = swz % NMB, bn = swz / NMB;
  const long m0 = (long)bm * BM, n0 = (long)bn * 256;
  const int NT = K >> 6;

  bf16x8 afA[MREP], afB[MREP], bfX[2], bfY[2];
  f32x4 acc[MREP][4] = {};

  auto stageA = [&](int nd, int kh, int t) {
    const bf16* src = A + m0 * K + t * 64 + kh * 32;
    char* dst = (char*)(&Abuf[nd][kh][0]) + w * 1024;
#pragma unroll
    for (int j = 0; j < ALD; j++) {
      int i = j * 512 + tid;
      GLOAD(src + (long)(i >> 2) * K + (i & 3) * 8, dst + j * 8192);
    }
  };
  auto stageB = [&](int nd, int kh, int t) {
    const bf16* src = Bt + n0 * K + t * 64 + kh * 32;
    char* dst = (char*)(&Bbuf[nd][kh][0]) + w * 1024;
#pragma unroll
    for (int j = 0; j < 2; j++) {
      int i = j * 512 + tid;
      GLOAD(src + (long)(i >> 2) * K + (i & 3) * 8, dst + j * 8192);
    }
  };
  auto readA = [&](bf16x8 (&af)[MREP], int d, int kh) {
#pragma unroll
    for (int mi = 0; mi < MREP; mi++)
      af[mi] = *(const bf16x8*)(
          &Abuf[d][kh][(wm * (BM / 2) + mi * 16 + lr) * 32 + lc * 8]);
  };
  auto readB = [&](bf16x8 (&bf)[2], int d, int kh, int nh) {
#pragma unroll
    for (int nj = 0; nj < 2; nj++)
      bf[nj] = *(const bf16x8*)(
          &Bbuf[d][kh][(wn * 64 + (nh * 2 + nj) * 16 + lr) * 32 + lc * 8]);
  };

#define MMQ(af, bf, NH)                                                        \
  {                                                                            \
    __builtin_amdgcn_s_setprio(1);                                             \
    _Pragma("unroll") for (int mi = 0; mi < MREP; mi++) {                      \
      acc[mi][NH * 2 + 0] = __builtin_amdgcn_mfma_f32_16x16x32_bf16(           \
          af[mi], bf[0], acc[mi][NH * 2 + 0], 0, 0, 0);                        \
      acc[mi][NH * 2 + 1] = __builtin_amdgcn_mfma_f32_16x16x32_bf16(           \
          af[mi], bf[1], acc[mi][NH * 2 + 1], 0, 0, 0);                        \
    }                                                                          \
    __builtin_amdgcn_s_setprio(0);                                             \
  }

  // prologue: stage tile 0 (order A-Klo, B-Klo, A-Khi, B-Khi)
  stageA(0, 0, 0);
  stageB(0, 0, 0);
  stageA(0, 1, 0);
  stageB(0, 1, 0);
  vm_wait<VMW>();  // oldest (A-Klo, B-Klo) landed
  barx();
  readA(afA, 0, 0);
  readB(bfX, 0, 0, 0);

  for (int t = 0; t < NT; t++) {
    const int d = t & 1, nd = d ^ 1;
    const int tn = (t + 1 < NT) ? t + 1 : t;  // dummy re-stage keeps counts uniform
    // ph0: MFMA (Klo, Nlo); read-ahead B(Klo,Nhi); stage A-Klo(t+1)
    stageA(nd, 0, tn);
    barx();
    readB(bfY, d, 0, 1);
    __builtin_amdgcn_sched_barrier(0);
    MMQ(afA, bfX, 0);
    barx();
    // ph1: MFMA (Klo, Nhi); read-ahead A(Khi)+B(Khi,Nlo); stage B-Klo(t+1)
    stageB(nd, 0, tn);
    vm_wait<VMW>();  // t's A-Khi, B-Khi landed
    barx();
    readA(afB, d, 1);
    readB(bfX, d, 1, 0);
    __builtin_amdgcn_sched_barrier(0);
    MMQ(afA, bfY, 1);
    barx();
    // ph2: MFMA (Khi, Nlo); read-ahead B(Khi,Nhi); stage A-Khi(t+1)
    stageA(nd, 1, tn);
    barx();
    readB(bfY, d, 1, 1);
    __builtin_amdgcn_sched_barrier(0);
    MMQ(afB, bfX, 0);
    barx();
    // ph3: MFMA (Khi, Nhi); read-ahead next tile (Klo,Nlo); stage B-Khi(t+1)
    stageB(nd, 1, tn);
    vm_wait<VMW>();  // t+1's A-Klo, B-Klo landed
    barx();
    readA(afA, nd, 0);
    readB(bfX, nd, 0, 0);
    __builtin_amdgcn_sched_barrier(0);
    MMQ(afB, bfY, 1);
    barx();
  }
  asm volatile("s_waitcnt vmcnt(0)" ::: "memory");  // drain dummy stages

  // epilogue: bias + store (C frag: col=l&15, row=(l>>4)*4+i)
#pragma unroll
  for (int nc = 0; nc < 4; nc++) {
    int gcol = (int)n0 + wn * 64 + nc * 16 + lr;
    float bv = bias[gcol];
    if (gcol < sb) bv *= 0.125f;
#pragma unroll
    for (int mi = 0; mi < MREP; mi++) {
#pragma unroll
      for (int i = 0; i < 4; i++) {
        long grow = m0 + wm * (BM / 2) + mi * 16 + lc * 4 + i;
        float v = acc[mi][nc][i] + bv;
        if constexpr (std::is_same<OutT, float>::value)
          C[grow * N + gcol] = v;
        else
          C[grow * N + gcol] = (bf16)v;
      }
    }
  }
#undef MMQ
}

// ---------------- causal flash attention, swapped-operand 32x32x16 ----------
// grid (8, B*H), 256 thr, 4 waves. Each block runs TWO q-strips of 128 rows:
// strip bx and strip 15-bx (uniform 36 K-tiles per block). Wave w owns 32
// q-rows. Softmax is per-lane (lane's col = q-row) + one shfl_xor(32).
__global__ __launch_bounds__(256) void flash_kernel(
    const bf16* __restrict__ Y, const bf16* __restrict__ Vt,
    bf16* __restrict__ O) {
  __shared__ __align__(16) bf16 Klds[2][64 * 64];  // [buf][k][d], swizzled
  __shared__ __align__(16) bf16 Vlds[2][64 * 64];  // [buf][d][k'], swizzled
  const int tid = threadIdx.x;
  const int w = tid >> 6, l = tid & 63;
  const int ln = l & 31, hi = l >> 5;
  const int bh = blockIdx.y;
  const int b = bh >> 4, h = bh & 15;
  const bf16* Kbase = Y + (long)(b * Tc) * N3 + Cc + h * 64;
  const bf16* Vbase = Vt + (long)bh * 64 * Tc;

  const int srow = tid >> 3, schunk = tid & 7;
  const int swz = (schunk ^ (srow & 7)) * 8;  // pre-swizzled source chunk
  const int wbase = w * 1024;
  char* KldsB = (char*)Klds;
  char* VldsB = (char*)Vlds;

  auto stage = [&](int buf, int kt0) {
    char* kd = KldsB + buf * 8192 + wbase;
    char* vd = VldsB + buf * 8192 + wbase;
    GLOAD(Kbase + (long)(kt0 + srow) * N3 + swz, kd);
    GLOAD(Kbase + (long)(kt0 + srow + 32) * N3 + swz, kd + 4096);
    GLOAD(Vbase + (long)srow * Tc + kt0 + swz, vd);
    GLOAD(Vbase + (long)(srow + 32) * Tc + kt0 + swz, vd + 4096);
  };

#pragma unroll 1
  for (int sp = 0; sp < 2; sp++) {
    const int st = sp ? (15 - (int)blockIdx.x) : (int)blockIdx.x;
    const int q0 = st * 128;
    const int qmin = q0 + w * 32;       // wave's first q row
    const int qg = qmin + ln;           // this lane's q row
    const long grow = (long)(b * Tc) + qg;

    // Q fragments (pre-scaled by 0.125 via weight fold): B[n=q][d-slot]
    bf16x8 aq[4];
#pragma unroll
    for (int dc = 0; dc < 4; dc++)
      aq[dc] = *(const bf16x8*)(Y + grow * N3 + h * 64 + dc * 16 + hi * 8);

    f32x16 ot[2] = {};
    float mrun = -__builtin_inff(), lrun = 0.f;
    const int nkt = 2 * st + 2;

    stage(0, 0);
    __syncthreads();

    for (int kt = 0; kt < nkt; kt++) {
      const int kt0 = kt * 64;
      if (kt + 1 < nkt) stage((kt + 1) & 1, kt0 + 64);
      const char* kb = KldsB + (kt & 1) * 8192;
      const char* vb = VldsB + (kt & 1) * 8192;

      if (kt0 <= qmin + 31) {
        // S^T = K Q^T : col(lane)=q, rows=k-pos
        f32x16 s[2];
        __builtin_amdgcn_s_setprio(1);
#pragma unroll
        for (int ks = 0; ks < 2; ks++) {
          f32x16 acc = {};
          const int krow = ks * 32 + ln;
          const int kswz = (krow & 7) << 4;
#pragma unroll
          for (int dc = 0; dc < 4; dc++) {
            bf16x8 ak =
                *(const bf16x8*)(kb + krow * 128 + ((dc * 32 + hi * 16) ^ kswz));
            acc = __builtin_amdgcn_mfma_f32_32x32x16_bf16(ak, aq[dc], acc, 0, 0, 0);
          }
          s[ks] = acc;
        }
        __builtin_amdgcn_s_setprio(0);
        // causal mask (diagonal tiles only; wave-uniform predicate)
        if (kt0 + 63 > qmin) {
#pragma unroll
          for (int ks = 0; ks < 2; ks++)
#pragma unroll
            for (int r = 0; r < 16; r++) {
              int kg = kt0 + ks * 32 + (r & 3) + 8 * (r >> 2) + 4 * hi;
              if (kg > qg) s[ks][r] = -__builtin_inff();
            }
        }
        // per-lane online softmax (lane holds 32 of 64 cols; partner the rest)
        float tm = s[0][0];
#pragma unroll
        for (int ks = 0; ks < 2; ks++)
#pragma unroll
          for (int r = 0; r < 16; r++) tm = fmaxf(tm, s[ks][r]);
        tm = fmaxf(tm, __shfl_xor(tm, 32));
        float mnew = fmaxf(mrun, tm);
        float factor = __expf(mrun - mnew);
        float lsum = 0.f;
#pragma unroll
        for (int ks = 0; ks < 2; ks++)
#pragma unroll
          for (int r = 0; r < 16; r++) {
            float p = __expf(s[ks][r] - mnew);
            s[ks][r] = p;
            lsum += p;
          }
        lsum += __shfl_xor(lsum, 32);
        lrun = lrun * factor + lsum;
        mrun = mnew;
#pragma unroll
        for (int db = 0; db < 2; db++)
#pragma unroll
          for (int r = 0; r < 16; r++) ot[db][r] *= factor;
        // pack P to bf16 pairs (natural order feeds PV via k-permuted V)
        uint32_t pu[2][8];
#pragma unroll
        for (int ks = 0; ks < 2; ks++)
#pragma unroll
          for (int j = 0; j < 8; j++)
            pu[ks][j] = pk2(s[ks][2 * j], s[ks][2 * j + 1]);
        // O^T += V^T P^T  (col=q matches softmax lane)
        __builtin_amdgcn_s_setprio(1);
#pragma unroll
        for (int ks = 0; ks < 2; ks++)
#pragma unroll
          for (int g = 0; g < 2; g++) {
            union { uint32_t u[4]; bf16x8 v; } pf;
            pf.u[0] = pu[ks][g * 4 + 0];
            pf.u[1] = pu[ks][g * 4 + 1];
            pf.u[2] = pu[ks][g * 4 + 2];
            pf.u[3] = pu[ks][g * 4 + 3];
#pragma unroll
            for (int db = 0; db < 2; db++) {
              const int vrow = db * 32 + ln;
              bf16x8 av = *(const bf16x8*)(
                  vb + vrow * 128 +
                  ((ks * 64 + g * 32 + hi * 16) ^ ((vrow & 7) << 4)));
              ot[db] = __builtin_amdgcn_mfma_f32_32x32x16_bf16(av, pf.v, ot[db],
                                                               0, 0, 0);
            }
          }
        __builtin_amdgcn_s_setprio(0);
      }
      __syncthreads();
    }

    // epilogue: assemble contiguous d-octets via one lane-pair exchange
    const float sc = 1.f / lrun;
#pragma unroll
    for (int db = 0; db < 2; db++) {
      uint32_t u[8];
#pragma unroll
      for (int j = 0; j < 8; j++)
        u[j] = pk2(ot[db][2 * j] * sc, ot[db][2 * j + 1] * sc);
#pragma unroll
      for (int g = 0; g < 2; g++) {
        uint32_t a0 = u[g * 4 + 0], a1 = u[g * 4 + 1];
        uint32_t a2 = u[g * 4 + 2], a3 = u[g * 4 + 3];
        uint32_t x0 = hi ? a0 : a2, x1 = hi ? a1 : a3;
        uint32_t y0 = (uint32_t)__shfl_xor((int)x0, 32);
        uint32_t y1 = (uint32_t)__shfl_xor((int)x1, 32);
        union { uint32_t u[4]; bf16x8 v; } f;
        f.u[0] = hi ? y0 : a0;
        f.u[1] = hi ? y1 : a1;
        f.u[2] = hi ? a2 : y0;
        f.u[3] = hi ? a3 : y1;
        *(bf16x8*)(O + grow * Cc + h * 64 + db * 32 + g * 16 + hi * 8) = f.v;
      }
    }
  }
}

extern "C" void kernel_launch(void* const* d_in, const int* in_sizes, int n_in,
                              void* d_out, int out_size, void* d_ws,
                              size_t ws_size, hipStream_t stream) {
  const float* x = (const float*)d_in[0];
  const float* qkv_w = (const float*)d_in[1];
  const float* qkv_b = (const float*)d_in[2];
  const float* out_w = (const float*)d_in[3];
  const float* out_b = (const float*)d_in[4];
  float* out = (float*)d_out;
  char* ws = (char*)d_ws;
  bf16* xb = (bf16*)(ws);                            // 16 MiB (x bf16)
  bf16* Obuf = (bf16*)(ws);                          // reuse after GEMM1
  bf16* wqkvT = (bf16*)(ws + (16ull << 20));         // 6 MiB
  bf16* woT = (bf16*)(ws + (22ull << 20));           // 2 MiB
  bf16* Ybuf = (bf16*)(ws + (24ull << 20));          // 48 MiB
  bf16* Vtb = (bf16*)(ws + (72ull << 20));           // 16 MiB  (total 88 MiB)

  cast_bf16_kernel<<<2048, 256, 0, stream>>>(x, xb, Mrows * Cc / 8);
  transpose_cast_kernel<<<dim3(N3 / 32, Cc / 32), dim3(32, 8), 0, stream>>>(
      qkv_w, wqkvT, Cc, N3, 0.125f, Cc);
  transpose_cast_kernel<<<dim3(Cc / 32, Cc / 32), dim3(32, 8), 0, stream>>>(
      out_w, woT, Cc, Cc, 1.0f, 0);
  // QKV: 256x256 tiles, grid 32*12 = 384 (384 % 8 == 0)
  gemm8_kernel<256, bf16><<<384, 512, 0, stream>>>(
      xb, wqkvT, qkv_b, Ybuf, Mrows, N3, Cc, Cc, Mrows / 256);
  transpose_v_kernel<<<dim3(Tc / 32, 2, Bc * Hc), dim3(32, 8), 0, stream>>>(
      Ybuf, Vtb);
  flash_kernel<<<dim3(8, Bc * Hc), 256, 0, stream>>>(Ybuf, Vtb, Obuf);
  // out-proj: 128x256 tiles, grid 64*4 = 256 (1 block/CU)
  gemm8_kernel<128, float><<<256, 512, 0, stream>>>(
      Obuf, woT, out_b, out, Mrows, Cc, Cc, 0, Mrows / 128);
}

// Round 8
// 274.825 us; speedup vs baseline: 1.1761x; 1.1761x over previous
//
#include <hip/hip_runtime.h>
#include <type_traits>

typedef __bf16 bf16;
typedef __attribute__((ext_vector_type(8))) __bf16 bf16x8;
typedef __attribute__((ext_vector_type(4))) float f32x4;
typedef __attribute__((ext_vector_type(16))) float f32x16;

constexpr int Bc = 4, Tc = 2048, Cc = 1024, Hc = 16;
constexpr int Mrows = Bc * Tc;   // 8192
constexpr int N3 = 3 * Cc;       // 3072

#define GLOAD(gp, lp)                                                          \
  __builtin_amdgcn_global_load_lds(                                           \
      (const __attribute__((address_space(1))) void*)(gp),                     \
      (__attribute__((address_space(3))) void*)(lp), 16, 0, 0)

__device__ __forceinline__ uint32_t pk2(float a, float b) {
  uint16_t x = __builtin_bit_cast(uint16_t, (bf16)a);
  uint16_t y = __builtin_bit_cast(uint16_t, (bf16)b);
  return (uint32_t)x | ((uint32_t)y << 16);
}

// ---------------- cast fp32 -> bf16, 8 elems/thread ----------------
__global__ __launch_bounds__(256) void cast_bf16_kernel(
    const float* __restrict__ in, bf16* __restrict__ out, int n8) {
  int i = blockIdx.x * blockDim.x + threadIdx.x;
  int stride = gridDim.x * blockDim.x;
  for (; i < n8; i += stride) {
    const float4* p = (const float4*)(in + (long)i * 8);
    float4 a = p[0], b = p[1];
    bf16x8 v;
    v[0] = (bf16)a.x; v[1] = (bf16)a.y; v[2] = (bf16)a.z; v[3] = (bf16)a.w;
    v[4] = (bf16)b.x; v[5] = (bf16)b.y; v[6] = (bf16)b.z; v[7] = (bf16)b.w;
    *(bf16x8*)(out + (long)i * 8) = v;
  }
}

// ---- transpose + cast: in[rows][cols] f32 -> out[cols][rows] bf16.
// Output rows < srows get multiplied by scale (fold 1/sqrt(D) into Wq).
__global__ __launch_bounds__(256) void transpose_cast_kernel(
    const float* __restrict__ in, bf16* __restrict__ out, int rows, int cols,
    float scale, int srows) {
  __shared__ float tile[32][33];
  int tx = threadIdx.x, ty = threadIdx.y;
  int r0 = blockIdx.y * 32, c0 = blockIdx.x * 32;
#pragma unroll
  for (int i = 0; i < 4; i++)
    tile[ty + 8 * i][tx] = in[(long)(r0 + ty + 8 * i) * cols + c0 + tx];
  __syncthreads();
#pragma unroll
  for (int i = 0; i < 4; i++) {
    int orow = c0 + ty + 8 * i;
    float v = tile[tx][ty + 8 * i];
    if (orow < srows) v *= scale;
    out[(long)orow * rows + r0 + tx] = (bf16)v;
  }
}

// ---- transpose V part of QKV: Y[.,2048+h*64+d] -> Vt[bh][d][t'] with
// quad-swapped t (bits 2<->3 of t&15) so PV reads b128 without lane exchange.
__global__ __launch_bounds__(256) void transpose_v_kernel(
    const bf16* __restrict__ Y, bf16* __restrict__ Vt) {
  __shared__ bf16 tile[32][33];
  int tx = threadIdx.x, ty = threadIdx.y;
  int t0 = blockIdx.x * 32;
  int d0 = blockIdx.y * 32;
  int bh = blockIdx.z;
  int b = bh >> 4, h = bh & 15;
  const bf16* src = Y + (long)(b * Tc) * N3 + 2 * Cc + h * 64;
#pragma unroll
  for (int i = 0; i < 4; i++)
    tile[ty + 8 * i][tx] = src[(long)(t0 + ty + 8 * i) * N3 + d0 + tx];
  __syncthreads();
  bf16* dst = Vt + (long)bh * 64 * Tc;
  int txp = (tx & 0x13) | ((tx & 4) << 1) | ((tx & 8) >> 1);  // quad swap
#pragma unroll
  for (int i = 0; i < 4; i++)
    dst[(long)(d0 + ty + 8 * i) * Tc + t0 + txp] = tile[tx][ty + 8 * i];
}

// ---------------- GEMM: C[M,N] = A[M,K](bf16) * Bt[N,K]^T + bias ------------
// m97 2-phase structure, 128x128 tile, BK=64 (halves barrier count vs BK=32).
// LDS rows are 128 B -> XOR-swizzle chunk^(row&7) on BOTH sides: staged via
// pre-swizzled global source (linear LDS dest), read with matching XOR.
// LDS 32 KB, 256 thr, 4 waves; ~4 blocks/CU residency.
template <typename OutT>
__global__ __launch_bounds__(256) void gemm_bt_kernel(
    const bf16* __restrict__ A, const bf16* __restrict__ Bt,
    const float* __restrict__ bias, OutT* __restrict__ Cout, int M, int N,
    int K, int sb) {
  __shared__ __align__(16) bf16 Alds[128 * 64];
  __shared__ __align__(16) bf16 Blds[128 * 64];
  const int tid = threadIdx.x;
  const int w = tid >> 6, l = tid & 63;
  const int m0 = blockIdx.x * 128, n0 = blockIdx.y * 128;
  const int wr = w >> 1, wc = w & 1;
  const int lr = l & 15, lc = l >> 4;
  f32x4 acc[4][4] = {};
  const int srow = tid >> 3;               // 0..31 (staging row within round)
  const int csw = (tid & 7) ^ (srow & 7);  // pre-swizzled source chunk
  const bf16* Ag = A + (long)(m0 + srow) * K + csw * 8;
  const bf16* Bg = Bt + (long)(n0 + srow) * K + csw * 8;
  char* AldsB = (char*)Alds;
  char* BldsB = (char*)Blds;
  const int lbase = tid * 16;        // linear LDS dest (wave-uniform + lane*16)
  const int rswz = (lr & 7) << 4;    // read-side XOR (row&7 == lr&7)

  for (int k0 = 0; k0 < K; k0 += 64) {
    __syncthreads();
#pragma unroll
    for (int r = 0; r < 4; r++) {
      GLOAD(Ag + k0 + (long)(r * 32) * K, AldsB + r * 4096 + lbase);
      GLOAD(Bg + k0 + (long)(r * 32) * K, BldsB + r * 4096 + lbase);
    }
    __syncthreads();
#pragma unroll
    for (int kk = 0; kk < 2; kk++) {
      bf16x8 af[4], bfr[4];
      const int koff = (kk * 64 + lc * 16) ^ rswz;
#pragma unroll
      for (int mi = 0; mi < 4; mi++)
        af[mi] =
            *(const bf16x8*)(AldsB + (wr * 64 + mi * 16 + lr) * 128 + koff);
#pragma unroll
      for (int ni = 0; ni < 4; ni++)
        bfr[ni] =
            *(const bf16x8*)(BldsB + (wc * 64 + ni * 16 + lr) * 128 + koff);
#pragma unroll
      for (int mi = 0; mi < 4; mi++)
#pragma unroll
        for (int ni = 0; ni < 4; ni++)
          acc[mi][ni] = __builtin_amdgcn_mfma_f32_16x16x32_bf16(
              af[mi], bfr[ni], acc[mi][ni], 0, 0, 0);
    }
  }
  // epilogue: bias + store (C frag: col=lr, row=lc*4+i)
#pragma unroll
  for (int mi = 0; mi < 4; mi++) {
#pragma unroll
    for (int ni = 0; ni < 4; ni++) {
      int gcol = n0 + wc * 64 + ni * 16 + lr;
      float bv = bias[gcol];
      if (gcol < sb) bv *= 0.125f;
#pragma unroll
      for (int i = 0; i < 4; i++) {
        int grow = m0 + wr * 64 + mi * 16 + lc * 4 + i;
        float v = acc[mi][ni][i] + bv;
        if constexpr (std::is_same<OutT, float>::value)
          Cout[(long)grow * N + gcol] = v;
        else
          Cout[(long)grow * N + gcol] = (bf16)v;
      }
    }
  }
}

// ---------------- causal flash attention, swapped-operand 32x32x16 ----------
// grid (8, B*H), 256 thr, 4 waves. Each block runs TWO q-strips of 128 rows:
// strip bx and strip 15-bx (uniform 36 K-tiles per block). Wave w owns 32
// q-rows. Softmax is per-lane (lane's col = q-row) + one shfl_xor(32).
__global__ __launch_bounds__(256) void flash_kernel(
    const bf16* __restrict__ Y, const bf16* __restrict__ Vt,
    bf16* __restrict__ O) {
  __shared__ __align__(16) bf16 Klds[2][64 * 64];  // [buf][k][d], swizzled
  __shared__ __align__(16) bf16 Vlds[2][64 * 64];  // [buf][d][k'], swizzled
  const int tid = threadIdx.x;
  const int w = tid >> 6, l = tid & 63;
  const int ln = l & 31, hi = l >> 5;
  const int bh = blockIdx.y;
  const int b = bh >> 4, h = bh & 15;
  const bf16* Kbase = Y + (long)(b * Tc) * N3 + Cc + h * 64;
  const bf16* Vbase = Vt + (long)bh * 64 * Tc;

  const int srow = tid >> 3, schunk = tid & 7;
  const int swz = (schunk ^ (srow & 7)) * 8;  // pre-swizzled source chunk
  const int wbase = w * 1024;
  char* KldsB = (char*)Klds;
  char* VldsB = (char*)Vlds;

  auto stage = [&](int buf, int kt0) {
    char* kd = KldsB + buf * 8192 + wbase;
    char* vd = VldsB + buf * 8192 + wbase;
    GLOAD(Kbase + (long)(kt0 + srow) * N3 + swz, kd);
    GLOAD(Kbase + (long)(kt0 + srow + 32) * N3 + swz, kd + 4096);
    GLOAD(Vbase + (long)srow * Tc + kt0 + swz, vd);
    GLOAD(Vbase + (long)(srow + 32) * Tc + kt0 + swz, vd + 4096);
  };

#pragma unroll 1
  for (int sp = 0; sp < 2; sp++) {
    const int st = sp ? (15 - (int)blockIdx.x) : (int)blockIdx.x;
    const int q0 = st * 128;
    const int qmin = q0 + w * 32;       // wave's first q row
    const int qg = qmin + ln;           // this lane's q row
    const long grow = (long)(b * Tc) + qg;

    // Q fragments (pre-scaled by 0.125 via weight fold): B[n=q][d-slot]
    bf16x8 aq[4];
#pragma unroll
    for (int dc = 0; dc < 4; dc++)
      aq[dc] = *(const bf16x8*)(Y + grow * N3 + h * 64 + dc * 16 + hi * 8);

    f32x16 ot[2] = {};
    float mrun = -__builtin_inff(), lrun = 0.f;
    const int nkt = 2 * st + 2;

    stage(0, 0);
    __syncthreads();

    for (int kt = 0; kt < nkt; kt++) {
      const int kt0 = kt * 64;
      if (kt + 1 < nkt) stage((kt + 1) & 1, kt0 + 64);
      const char* kb = KldsB + (kt & 1) * 8192;
      const char* vb = VldsB + (kt & 1) * 8192;

      if (kt0 <= qmin + 31) {
        // S^T = K Q^T : col(lane)=q, rows=k-pos
        f32x16 s[2];
        __builtin_amdgcn_s_setprio(1);
#pragma unroll
        for (int ks = 0; ks < 2; ks++) {
          f32x16 acc = {};
          const int krow = ks * 32 + ln;
          const int kswz = (krow & 7) << 4;
#pragma unroll
          for (int dc = 0; dc < 4; dc++) {
            bf16x8 ak =
                *(const bf16x8*)(kb + krow * 128 + ((dc * 32 + hi * 16) ^ kswz));
            acc = __builtin_amdgcn_mfma_f32_32x32x16_bf16(ak, aq[dc], acc, 0, 0, 0);
          }
          s[ks] = acc;
        }
        __builtin_amdgcn_s_setprio(0);
        // causal mask (diagonal tiles only; wave-uniform predicate)
        if (kt0 + 63 > qmin) {
#pragma unroll
          for (int ks = 0; ks < 2; ks++)
#pragma unroll
            for (int r = 0; r < 16; r++) {
              int kg = kt0 + ks * 32 + (r & 3) + 8 * (r >> 2) + 4 * hi;
              if (kg > qg) s[ks][r] = -__builtin_inff();
            }
        }
        // per-lane online softmax (lane holds 32 of 64 cols; partner the rest)
        float tm = s[0][0];
#pragma unroll
        for (int ks = 0; ks < 2; ks++)
#pragma unroll
          for (int r = 0; r < 16; r++) tm = fmaxf(tm, s[ks][r]);
        tm = fmaxf(tm, __shfl_xor(tm, 32));
        float mnew = fmaxf(mrun, tm);
        float factor = __expf(mrun - mnew);
        float lsum = 0.f;
#pragma unroll
        for (int ks = 0; ks < 2; ks++)
#pragma unroll
          for (int r = 0; r < 16; r++) {
            float p = __expf(s[ks][r] - mnew);
            s[ks][r] = p;
            lsum += p;
          }
        lsum += __shfl_xor(lsum, 32);
        lrun = lrun * factor + lsum;
        mrun = mnew;
#pragma unroll
        for (int db = 0; db < 2; db++)
#pragma unroll
          for (int r = 0; r < 16; r++) ot[db][r] *= factor;
        // pack P to bf16 pairs (natural order feeds PV via k-permuted V)
        uint32_t pu[2][8];
#pragma unroll
        for (int ks = 0; ks < 2; ks++)
#pragma unroll
          for (int j = 0; j < 8; j++)
            pu[ks][j] = pk2(s[ks][2 * j], s[ks][2 * j + 1]);
        // O^T += V^T P^T  (col=q matches softmax lane)
        __builtin_amdgcn_s_setprio(1);
#pragma unroll
        for (int ks = 0; ks < 2; ks++)
#pragma unroll
          for (int g = 0; g < 2; g++) {
            union { uint32_t u[4]; bf16x8 v; } pf;
            pf.u[0] = pu[ks][g * 4 + 0];
            pf.u[1] = pu[ks][g * 4 + 1];
            pf.u[2] = pu[ks][g * 4 + 2];
            pf.u[3] = pu[ks][g * 4 + 3];
#pragma unroll
            for (int db = 0; db < 2; db++) {
              const int vrow = db * 32 + ln;
              bf16x8 av = *(const bf16x8*)(
                  vb + vrow * 128 +
                  ((ks * 64 + g * 32 + hi * 16) ^ ((vrow & 7) << 4)));
              ot[db] = __builtin_amdgcn_mfma_f32_32x32x16_bf16(av, pf.v, ot[db],
                                                               0, 0, 0);
            }
          }
        __builtin_amdgcn_s_setprio(0);
      }
      __syncthreads();
    }

    // epilogue: assemble contiguous d-octets via one lane-pair exchange
    const float sc = 1.f / lrun;
#pragma unroll
    for (int db = 0; db < 2; db++) {
      uint32_t u[8];
#pragma unroll
      for (int j = 0; j < 8; j++)
        u[j] = pk2(ot[db][2 * j] * sc, ot[db][2 * j + 1] * sc);
#pragma unroll
      for (int g = 0; g < 2; g++) {
        uint32_t a0 = u[g * 4 + 0], a1 = u[g * 4 + 1];
        uint32_t a2 = u[g * 4 + 2], a3 = u[g * 4 + 3];
        uint32_t x0 = hi ? a0 : a2, x1 = hi ? a1 : a3;
        uint32_t y0 = (uint32_t)__shfl_xor((int)x0, 32);
        uint32_t y1 = (uint32_t)__shfl_xor((int)x1, 32);
        union { uint32_t u[4]; bf16x8 v; } f;
        f.u[0] = hi ? y0 : a0;
        f.u[1] = hi ? y1 : a1;
        f.u[2] = hi ? a2 : y0;
        f.u[3] = hi ? a3 : y1;
        *(bf16x8*)(O + grow * Cc + h * 64 + db * 32 + g * 16 + hi * 8) = f.v;
      }
    }
  }
}

extern "C" void kernel_launch(void* const* d_in, const int* in_sizes, int n_in,
                              void* d_out, int out_size, void* d_ws,
                              size_t ws_size, hipStream_t stream) {
  const float* x = (const float*)d_in[0];
  const float* qkv_w = (const float*)d_in[1];
  const float* qkv_b = (const float*)d_in[2];
  const float* out_w = (const float*)d_in[3];
  const float* out_b = (const float*)d_in[4];
  float* out = (float*)d_out;
  char* ws = (char*)d_ws;
  bf16* xb = (bf16*)(ws);                            // 16 MiB (x bf16)
  bf16* Obuf = (bf16*)(ws);                          // reuse after GEMM1
  bf16* wqkvT = (bf16*)(ws + (16ull << 20));         // 6 MiB
  bf16* woT = (bf16*)(ws + (22ull << 20));           // 2 MiB
  bf16* Ybuf = (bf16*)(ws + (24ull << 20));          // 48 MiB
  bf16* Vtb = (bf16*)(ws + (72ull << 20));           // 16 MiB  (total 88 MiB)

  cast_bf16_kernel<<<2048, 256, 0, stream>>>(x, xb, Mrows * Cc / 8);
  transpose_cast_kernel<<<dim3(N3 / 32, Cc / 32), dim3(32, 8), 0, stream>>>(
      qkv_w, wqkvT, Cc, N3, 0.125f, Cc);
  transpose_cast_kernel<<<dim3(Cc / 32, Cc / 32), dim3(32, 8), 0, stream>>>(
      out_w, woT, Cc, Cc, 1.0f, 0);
  gemm_bt_kernel<bf16><<<dim3(Mrows / 128, N3 / 128), 256, 0, stream>>>(
      xb, wqkvT, qkv_b, Ybuf, Mrows, N3, Cc, Cc);
  transpose_v_kernel<<<dim3(Tc / 32, 2, Bc * Hc), dim3(32, 8), 0, stream>>>(
      Ybuf, Vtb);
  flash_kernel<<<dim3(8, Bc * Hc), 256, 0, stream>>>(Ybuf, Vtb, Obuf);
  gemm_bt_kernel<float><<<dim3(Mrows / 128, Cc / 128), 256, 0, stream>>>(
      Obuf, woT, out_b, out, Mrows, Cc, Cc, 0);
}